// Round 4
// baseline (263.845 us; speedup 1.0000x reference)
//
#include <hip/hip_runtime.h>
#include <cstddef>

static constexpr int TT = 64;    // decoder steps
static constexpr int BB = 8;     // batch
static constexpr int SS = 512;   // source length
static constexpr int HH = 512;   // hidden
static constexpr int NB = 256;   // grid size (persistent kernel)

typedef __attribute__((ext_vector_type(8))) short bf16x8;
typedef __attribute__((ext_vector_type(4))) float f32x4;

__device__ __forceinline__ float fast_tanh(float x) {
  float e = __expf(2.0f * x);
  return 1.0f - 2.0f * __builtin_amdgcn_rcpf(e + 1.0f);
}
__device__ __forceinline__ unsigned short f2bf(float f) {
  unsigned u = __float_as_uint(f);
  return (unsigned short)((u + 0x7FFFu + ((u >> 16) & 1u)) >> 16);   // RNE
}

// Monotone grid barrier: counter zeroed by hipMemsetAsync each launch.
// AGENT-scope acq/rel -> correct cross-XCD visibility (compiler emits L2 ops).
__device__ __forceinline__ void gbar(unsigned* ctr, unsigned target) {
  __syncthreads();
  if (threadIdx.x == 0) {
    __hip_atomic_fetch_add(ctr, 1u, __ATOMIC_ACQ_REL, __HIP_MEMORY_SCOPE_AGENT);
    while (__hip_atomic_load(ctr, __ATOMIC_ACQUIRE, __HIP_MEMORY_SCOPE_AGENT) < target)
      __builtin_amdgcn_s_sleep(8);
  }
  __syncthreads();
}

// 64x64 bf16 MFMA tile over K range [kbeg,kend). 256 thr / 4 waves.
// mfma_f32_16x16x32_bf16; C/D: col=lane&15, row=(lane>>4)*4+reg (verified r2/r3).
template<int LDA, int LDB>
__device__ __forceinline__ void gemm_tile(const unsigned short* __restrict__ A,
                                          const unsigned short* __restrict__ BT,
                                          int m0, int n0, int kbeg, int kend,
                                          unsigned short (*As)[72],
                                          unsigned short (*Bs)[72],
                                          f32x4 acc[4]) {
  const int tid = threadIdx.x, w = tid >> 6, lane = tid & 63;
  const int lr = tid >> 2, lk = (tid & 3) * 16;
  const int fm = w * 16 + (lane & 15), fk = (lane >> 4) * 8;
  for (int k0 = kbeg; k0 < kend; k0 += 64) {
    __syncthreads();   // protect LDS reuse
    const uint4* ga = (const uint4*)(A + (size_t)(m0 + lr) * LDA + k0 + lk);
    const uint4* gb = (const uint4*)(BT + (size_t)(n0 + lr) * LDB + k0 + lk);
    uint4 a0 = ga[0], a1 = ga[1], b0 = gb[0], b1 = gb[1];
    *(uint4*)&As[lr][lk] = a0;  *(uint4*)&As[lr][lk + 8] = a1;
    *(uint4*)&Bs[lr][lk] = b0;  *(uint4*)&Bs[lr][lk + 8] = b1;
    __syncthreads();
#pragma unroll
    for (int ks = 0; ks < 2; ++ks) {
      bf16x8 af = *(const bf16x8*)&As[fm][ks * 32 + fk];
#pragma unroll
      for (int j = 0; j < 4; ++j) {
        bf16x8 bf = *(const bf16x8*)&Bs[j * 16 + (lane & 15)][ks * 32 + fk];
        acc[j] = __builtin_amdgcn_mfma_f32_16x16x32_bf16(af, bf, acc[j], 0, 0, 0);
      }
    }
  }
}

__global__ __launch_bounds__(256)
void k_fused(const float* __restrict__ dec, const float* __restrict__ enc,
             const float* __restrict__ cov, const float* __restrict__ Wq,
             const float* __restrict__ bq, const float* __restrict__ Wc,
             const float* __restrict__ v, const float* __restrict__ Wo,
             const float* __restrict__ bo, const float* __restrict__ wcov,
             unsigned short* __restrict__ encpb, unsigned short* __restrict__ decb,
             unsigned short* __restrict__ concatb,
             unsigned short* __restrict__ WqT, unsigned short* __restrict__ WcT,
             unsigned short* __restrict__ WoT,
             float* __restrict__ Ea1, float* __restrict__ Ea2,
             float* __restrict__ scb, float* __restrict__ v2,
             float* __restrict__ Vsum, float* __restrict__ part,
             float* __restrict__ attn_h, float* __restrict__ align_out,
             unsigned* __restrict__ ctr) {
  __shared__ __align__(16) char smem[18496];
  const int g = blockIdx.x, tid = threadIdx.x;

  // ================= Phase A: prep =================
  {
    // enc tanh -> bf16, rows bs = g*16 .. +16
    for (int r = 0; r < 16; ++r) {
      const int bs = g * 16 + r, s = bs & 511, b = bs >> 9;
      const float2 ev = *(const float2*)(enc + (size_t)(s * BB + b) * HH + 2 * tid);
      const float cv = cov[bs];
      const float2 wv = *(const float2*)(wcov + 2 * tid);
      const unsigned lo = f2bf(fast_tanh(ev.x + cv * wv.x));
      const unsigned hi = f2bf(fast_tanh(ev.y + cv * wv.y));
      *(unsigned*)(encpb + (size_t)bs * HH + 2 * tid) = lo | (hi << 16);
    }
    // dec pack, rows m = 2g, 2g+1 (also concat right half)
    for (int r = 0; r < 2; ++r) {
      const int m = g * 2 + r, t = m & 63, b = m >> 6;
      const float2 dv = *(const float2*)(dec + (size_t)(t * BB + b) * HH + 2 * tid);
      const unsigned pv = (unsigned)f2bf(dv.x) | ((unsigned)f2bf(dv.y) << 16);
      *(unsigned*)(decb + (size_t)m * HH + 2 * tid) = pv;
      *(unsigned*)(concatb + (size_t)m * 1024 + 512 + 2 * tid) = pv;
    }
    // weight transposes: 1024 32x32 tiles, 4 per block
    float (*tile)[33] = (float(*)[33])smem;
    const int r = tid >> 3, c4 = (tid & 7) * 4;
    for (int i = 0; i < 4; ++i) {
      const int tau = g + NB * i;
      const float* W; unsigned short* WT; int KT, n0, k0;
      if (tau < 256)      { W = Wq; WT = WqT; KT = 512;  n0 = (tau & 15) * 32; k0 = (tau >> 4) * 32; }
      else if (tau < 512) { int u = tau - 256; W = Wc; WT = WcT; KT = 512;  n0 = (u & 15) * 32; k0 = (u >> 4) * 32; }
      else                { int u = tau - 512; W = Wo; WT = WoT; KT = 1024; n0 = (u & 15) * 32; k0 = (u >> 4) * 32; }
      __syncthreads();
      const float4 wv = *(const float4*)(W + (size_t)(k0 + r) * 512 + n0 + c4);
      tile[r][c4] = wv.x; tile[r][c4 + 1] = wv.y; tile[r][c4 + 2] = wv.z; tile[r][c4 + 3] = wv.w;
      __syncthreads();
      ushort4 ov;
      ov.x = f2bf(tile[c4][r]);     ov.y = f2bf(tile[c4 + 1][r]);
      ov.z = f2bf(tile[c4 + 2][r]); ov.w = f2bf(tile[c4 + 3][r]);
      *(ushort4*)(WT + (size_t)(n0 + r) * KT + k0 + c4) = ov;
    }
    // v2 / Vsum (block 0)
    if (g == 0) {
      __syncthreads();
      float* rb = (float*)smem;
      const float va = v[tid], vb = v[tid + 256];
      v2[tid] = 2.0f * va; v2[tid + 256] = 2.0f * vb;
      rb[tid] = va + vb;
      __syncthreads();
      for (int off = 128; off; off >>= 1) {
        if (tid < off) rb[tid] += rb[tid + off];
        __syncthreads();
      }
      if (tid == 0) Vsum[0] = rb[0];
    }
  }
  gbar(ctr, NB);

  // ================= Phase B: a1/a2 GEMMs + exp epilogue =================
  {
    auto As = (unsigned short(*)[72])smem;
    auto Bs = (unsigned short(*)[72])(smem + 9216);
    const int lane = tid & 63, w = tid >> 6, col = lane & 15, rq = lane >> 4;
    for (int i = 0; i < 3; ++i) {
      const int tau = g + NB * i;
      if (tau >= 576) break;
      const unsigned short *A, *BT; float* C; const float* bias; int m0, n0;
      if (tau < 64) { A = decb;  BT = WqT; C = Ea1; bias = bq;     m0 = (tau >> 3) * 64; n0 = (tau & 7) * 64; }
      else { int u = tau - 64; A = encpb; BT = WcT; C = Ea2; bias = nullptr; m0 = (u >> 3) * 64; n0 = (u & 7) * 64; }
      f32x4 acc[4] = {};
      gemm_tile<512, 512>(A, BT, m0, n0, 0, 512, As, Bs, acc);
#pragma unroll
      for (int j = 0; j < 4; ++j) {
        const int n = n0 + j * 16 + col;
        const float bv = bias ? bias[n] : 0.0f;
#pragma unroll
        for (int r2 = 0; r2 < 4; ++r2) {
          const int m = m0 + w * 16 + rq * 4 + r2;
          float val = acc[j][r2] + bv;
          // clamp +-10.5: keeps pair-product x1*x2 <= e^42 (no overflow);
          // tanh(10.5)=1-1.5e-9 so clamping is exact to fp32 tolerance.
          val = fminf(fmaxf(val, -10.5f), 10.5f);
          C[(size_t)m * 512 + n] = __expf(2.0f * val);
        }
      }
    }
  }
  gbar(ctr, 2 * NB);

  // ================= Phase C: scores (pair-rcp) =================
  // sc[b,t,s] = V - sum_h 2 v_h / (Ea1*Ea2 + 1); pairs share one rcp.
  {
    float (*ea1s)[512] = (float(*)[512])smem;
    float* v2s = (float*)(smem + 8192);
    const int b = g & 7, tq = (g >> 3) & 15, j0 = g >> 7;
#pragma unroll
    for (int i = 0; i < 4; ++i) {
      const float* row = Ea1 + (size_t)(b * TT + tq * 4 + i) * HH;
      ea1s[i][tid] = row[tid]; ea1s[i][tid + 256] = row[tid + 256];
    }
    v2s[tid] = v2[tid]; v2s[tid + 256] = v2[tid + 256];
    __syncthreads();
    const float V = Vsum[0];
    const int wv = tid >> 6, lane = tid & 63, hq = lane & 3, sl = lane >> 2;
    for (int kk = 0; kk < 4; ++kk) {
      const int s = (j0 + 2 * kk) * 64 + wv * 16 + sl;
      const float* erow = Ea2 + (size_t)(b * SS + s) * HH;
      float acc[4] = {0.f, 0.f, 0.f, 0.f};
#pragma unroll 4
      for (int it = 0; it < 32; ++it) {
        const int h = it * 16 + hq * 4;
        const float4 e2 = *(const float4*)(erow + h);
        const float4 vv = *(const float4*)&v2s[h];
#pragma unroll
        for (int i = 0; i < 4; ++i) {
          const float4 e1 = *(const float4*)&ea1s[i][h];
          const float x1 = fmaf(e1.x, e2.x, 1.0f), x2 = fmaf(e1.y, e2.y, 1.0f);
          const float x3 = fmaf(e1.z, e2.z, 1.0f), x4 = fmaf(e1.w, e2.w, 1.0f);
          const float r12 = __builtin_amdgcn_rcpf(x1 * x2);
          const float r34 = __builtin_amdgcn_rcpf(x3 * x4);
          const float n12 = fmaf(vv.x, x2, vv.y * x1);
          const float n34 = fmaf(vv.z, x4, vv.w * x3);
          acc[i] = fmaf(n12, r12, acc[i]);
          acc[i] = fmaf(n34, r34, acc[i]);
        }
      }
#pragma unroll
      for (int i = 0; i < 4; ++i) {
        acc[i] += __shfl_xor(acc[i], 1);
        acc[i] += __shfl_xor(acc[i], 2);
      }
      if (hq == 0) {
#pragma unroll
        for (int i = 0; i < 4; ++i)
          scb[(size_t)(b * TT + tq * 4 + i) * SS + s] = V - acc[i];
      }
    }
  }
  gbar(ctr, 3 * NB);

  // ================= Phase D: softmax + context =================
  {
    float (*al)[512] = (float(*)[512])smem;
    float (*red)[4] = (float(*)[4])(smem + 4096);
    const int b = g & 7, t0 = (g >> 3) * 2;
    const int wave = tid >> 6, lane = tid & 63;

    const float* r0 = scb + (size_t)(b * TT + t0) * SS;
    const float* r1 = r0 + SS;
    const float x00 = r0[tid], x01 = r0[tid + 256];
    const float x10 = r1[tid], x11 = r1[tid + 256];

    float m0 = fmaxf(x00, x01), m1 = fmaxf(x10, x11);
#pragma unroll
    for (int off = 32; off; off >>= 1) {
      m0 = fmaxf(m0, __shfl_xor(m0, off));
      m1 = fmaxf(m1, __shfl_xor(m1, off));
    }
    if (lane == 0) { red[0][wave] = m0; red[1][wave] = m1; }
    __syncthreads();
    m0 = fmaxf(fmaxf(red[0][0], red[0][1]), fmaxf(red[0][2], red[0][3]));
    m1 = fmaxf(fmaxf(red[1][0], red[1][1]), fmaxf(red[1][2], red[1][3]));
    __syncthreads();

    const float e00 = __expf(x00 - m0), e01 = __expf(x01 - m0);
    const float e10 = __expf(x10 - m1), e11 = __expf(x11 - m1);
    float s0 = e00 + e01, s1 = e10 + e11;
#pragma unroll
    for (int off = 32; off; off >>= 1) {
      s0 += __shfl_xor(s0, off);
      s1 += __shfl_xor(s1, off);
    }
    if (lane == 0) { red[0][wave] = s0; red[1][wave] = s1; }
    __syncthreads();
    s0 = red[0][0] + red[0][1] + red[0][2] + red[0][3];
    s1 = red[1][0] + red[1][1] + red[1][2] + red[1][3];
    const float rs0 = __builtin_amdgcn_rcpf(s0);
    const float rs1 = __builtin_amdgcn_rcpf(s1);

    const float a00 = e00 * rs0, a01 = e01 * rs0;
    const float a10 = e10 * rs1, a11 = e11 * rs1;
    float* ao0 = align_out + (size_t)(t0 + 0) * BB * SS + b * SS;
    float* ao1 = align_out + (size_t)(t0 + 1) * BB * SS + b * SS;
    ao0[tid] = a00; ao0[tid + 256] = a01;
    ao1[tid] = a10; ao1[tid + 256] = a11;
    al[0][tid] = a00; al[0][tid + 256] = a01;
    al[1][tid] = a10; al[1][tid + 256] = a11;
    __syncthreads();

    const unsigned* ep = (const unsigned*)(encpb + (size_t)b * SS * HH);
    float c00 = 0.f, c01 = 0.f, c10 = 0.f, c11 = 0.f;
#pragma unroll 16
    for (int s2 = 0; s2 < SS; ++s2) {
      const unsigned u = ep[s2 * 256 + tid];
      const float elo = __uint_as_float(u << 16);
      const float ehi = __uint_as_float(u & 0xffff0000u);
      const float av0 = al[0][s2], av1 = al[1][s2];
      c00 = fmaf(av0, elo, c00); c01 = fmaf(av0, ehi, c01);
      c10 = fmaf(av1, elo, c10); c11 = fmaf(av1, ehi, c11);
    }
    unsigned* cb0 = (unsigned*)(concatb + (size_t)(b * TT + t0) * 1024);
    unsigned* cb1 = (unsigned*)(concatb + (size_t)(b * TT + t0 + 1) * 1024);
    cb0[tid] = (unsigned)f2bf(c00) | ((unsigned)f2bf(c01) << 16);
    cb1[tid] = (unsigned)f2bf(c10) | ((unsigned)f2bf(c11) << 16);
  }
  gbar(ctr, 4 * NB);

  // ================= Phase E: out GEMM, split-K x4 =================
  {
    auto As = (unsigned short(*)[72])smem;
    auto Bs = (unsigned short(*)[72])(smem + 9216);
    const int tau = g >> 2, kc = g & 3;
    const int m0 = (tau >> 3) * 64, n0 = (tau & 7) * 64;
    f32x4 acc[4] = {};
    gemm_tile<1024, 1024>(concatb, WoT, m0, n0, kc * 256, kc * 256 + 256, As, Bs, acc);
    const int lane = tid & 63, w = tid >> 6, col = lane & 15, rq = lane >> 4;
    float* P = part + (size_t)g * 4096;
#pragma unroll
    for (int j = 0; j < 4; ++j)
#pragma unroll
      for (int r2 = 0; r2 < 4; ++r2)
        P[(w * 16 + rq * 4 + r2) * 64 + j * 16 + col] = acc[j][r2];
  }
  gbar(ctr, 5 * NB);

  // ================= Phase F: reduce split-K + bias + scatter =================
  {
    const int tau = g >> 2, q = g & 3;
    const int m0 = (tau >> 3) * 64, n0 = (tau & 7) * 64;
    const float* P = part + (size_t)tau * 4 * 4096;
#pragma unroll
    for (int jj = 0; jj < 4; ++jj) {
      const int i = jj * 256 + tid;
      const int ml = q * 16 + (i >> 6), nl = i & 63;
      float acc2 = bo[n0 + nl];
#pragma unroll
      for (int kc = 0; kc < 4; ++kc) acc2 += P[kc * 4096 + ml * 64 + nl];
      const int m = m0 + ml, bb2 = m >> 6, t = m & 63;
      attn_h[(size_t)(t * BB + bb2) * HH + n0 + nl] = acc2;
    }
  }
}

// ---------------------------------------------------------------------------
extern "C" void kernel_launch(void* const* d_in, const int* in_sizes, int n_in,
                              void* d_out, int out_size, void* d_ws, size_t ws_size,
                              hipStream_t stream) {
  const float* dec  = (const float*)d_in[0];
  const float* enc  = (const float*)d_in[1];
  const float* cov  = (const float*)d_in[2];
  const float* Wq   = (const float*)d_in[3];
  const float* bq   = (const float*)d_in[4];
  const float* Wc   = (const float*)d_in[5];
  const float* v    = (const float*)d_in[6];
  const float* Wo   = (const float*)d_in[7];
  const float* bo   = (const float*)d_in[8];
  const float* wcov = (const float*)d_in[9];

  float* out = (float*)d_out;
  float* attn_h    = out;                         // [T,B,H]
  float* align_out = out + (size_t)TT * BB * HH;  // [T,B,S]

  char* w = (char*)d_ws;
  const size_t MB = 1024 * 1024;
  unsigned short* encpb   = (unsigned short*)(w);            // 4 MB
  unsigned short* WqT     = (unsigned short*)(w + 4 * MB);   // 0.5 MB
  unsigned short* WcT     = (unsigned short*)(w + 5 * MB);   // 0.5 MB
  unsigned short* WoT     = (unsigned short*)(w + 6 * MB);   // 1 MB
  unsigned short* decb    = (unsigned short*)(w + 7 * MB);   // 0.5 MB
  unsigned short* concatb = (unsigned short*)(w + 8 * MB);   // 1 MB
  float*          Ea1     = (float*)(w + 9 * MB);            // 1 MB
  float*          Ea2     = (float*)(w + 10 * MB);           // 8 MB
  float*          scb     = (float*)(w + 18 * MB);           // 1 MB
  float*          v2      = (float*)(w + 19 * MB);           // 2 KB
  float*          Vsum    = (float*)(w + 19 * MB + 4096);    // 4 B
  float*          part    = (float*)(w + 20 * MB);           // 4 MB
  unsigned*       ctr     = (unsigned*)(w + 30 * MB);        // barrier counter

  hipMemsetAsync(ctr, 0, 128, stream);
  k_fused<<<NB, 256, 0, stream>>>(dec, enc, cov, Wq, bq, Wc, v, Wo, bo, wcov,
                                  encpb, decb, concatb, WqT, WcT, WoT,
                                  Ea1, Ea2, scb, v2, Vsum, part,
                                  attn_h, align_out, ctr);
}

// Round 5
// 144.001 us; speedup vs baseline: 1.8322x; 1.8322x over previous
//
#include <hip/hip_runtime.h>
#include <cstddef>

static constexpr int TT = 64;    // decoder steps
static constexpr int BB = 8;     // batch
static constexpr int SS = 512;   // source length
static constexpr int HH = 512;   // hidden

typedef __attribute__((ext_vector_type(8))) short bf16x8;
typedef __attribute__((ext_vector_type(4))) float f32x4;

__device__ __forceinline__ float fast_tanh(float x) {
  float e = __expf(2.0f * x);
  return 1.0f - 2.0f * __builtin_amdgcn_rcpf(e + 1.0f);
}
__device__ __forceinline__ unsigned short f2bf(float f) {
  unsigned u = __float_as_uint(f);
  return (unsigned short)((u + 0x7FFFu + ((u >> 16) & 1u)) >> 16);   // RNE
}

// ---------------------------------------------------------------------------
// k_prep — all preprocessing in one launch:
//  [0,8192):      encpb = bf16(tanh(enc + cov*wcov))
//  [8192,9216):   decb pack + concat right half
//  [9216,10240):  weight transposes Wq,Wc,Wo (32x32 tiles)
//  10240:         v2[h]=2v[h], Vsum=sum v
//  [10241,10753): attn_h[row] = bo  (bias init for k_out's atomic split-K)
// ---------------------------------------------------------------------------
__global__ __launch_bounds__(256)
void k_prep(const float* __restrict__ enc, const float* __restrict__ cov,
            const float* __restrict__ wcov, const float* __restrict__ dec,
            const float* __restrict__ Wq, const float* __restrict__ Wc,
            const float* __restrict__ Wo, const float* __restrict__ v,
            const float* __restrict__ bo,
            unsigned short* __restrict__ encpb, unsigned short* __restrict__ decb,
            unsigned short* __restrict__ concatb,
            unsigned short* __restrict__ WqT, unsigned short* __restrict__ WcT,
            unsigned short* __restrict__ WoT,
            float* __restrict__ v2, float* __restrict__ Vsum,
            float* __restrict__ attn_h) {
  __shared__ float tile[32][33];
  const int blk = blockIdx.x, tid = threadIdx.x;

  if (blk < 8192) {
    const int idx = blk * 256 + tid;          // B*S*H
    const int h = idx & 511;
    const int bs = idx >> 9;
    const int s = bs & 511, b = bs >> 9;
    const float x = enc[(size_t)(s * BB + b) * HH + h] + cov[bs] * wcov[h];
    encpb[idx] = f2bf(fast_tanh(x));
  } else if (blk < 9216) {
    const int idx = (blk - 8192) * 256 + tid; // 512*512
    const int h = idx & 511, m = idx >> 9;    // m=b*64+t
    const int b = m >> 6, t = m & 63;
    const unsigned short val = f2bf(dec[(size_t)(t * BB + b) * HH + h]);
    decb[idx] = val;
    concatb[(size_t)m * 1024 + 512 + h] = val;
  } else if (blk < 10240) {
    int l = blk - 9216;
    const float* W; unsigned short* WT; int KT;
    if (l < 256)      { W = Wq; WT = WqT; KT = 512; }
    else if (l < 512) { W = Wc; WT = WcT; KT = 512; l -= 256; }
    else              { W = Wo; WT = WoT; KT = 1024; l -= 512; }
    const int n0 = (l & 15) * 32, k0 = (l >> 4) * 32;
    const int r = tid >> 3, c4 = (tid & 7) * 4;
    const float4 w = *(const float4*)(W + (size_t)(k0 + r) * 512 + n0 + c4);
    tile[r][c4 + 0] = w.x; tile[r][c4 + 1] = w.y;
    tile[r][c4 + 2] = w.z; tile[r][c4 + 3] = w.w;
    __syncthreads();
    unsigned short* o = WT + (size_t)(n0 + r) * KT + k0 + c4;
#pragma unroll
    for (int i = 0; i < 4; ++i) o[i] = f2bf(tile[c4 + i][r]);
  } else if (blk == 10240) {
    __shared__ float rb[256];
    const float va = v[tid], vb = v[tid + 256];
    v2[tid] = 2.0f * va;
    v2[tid + 256] = 2.0f * vb;
    rb[tid] = va + vb;
    __syncthreads();
    for (int off = 128; off; off >>= 1) {
      if (tid < off) rb[tid] += rb[tid + off];
      __syncthreads();
    }
    if (tid == 0) Vsum[0] = rb[0];
  } else {
    // attn_h bias init: row = blk-10241 (0..511), any order; k_out atomicAdds on top
    const int row = blk - 10241;
    const float2 bv = *(const float2*)(bo + 2 * tid);
    *(float2*)(attn_h + (size_t)row * 512 + 2 * tid) = bv;
  }
}

// ---------------------------------------------------------------------------
// 64x64 bf16 MFMA tile over K range. 256 thr / 4 waves.
// C/D layout: col=lane&15, row=(lane>>4)*4+reg (verified r2/r3).
// ---------------------------------------------------------------------------
template<int LDA, int LDB>
__device__ __forceinline__ void gemm_tile(const unsigned short* __restrict__ A,
                                          const unsigned short* __restrict__ BT,
                                          int m0, int n0, int kbeg, int kend,
                                          unsigned short (*As)[72],
                                          unsigned short (*Bs)[72],
                                          f32x4 acc[4]) {
  const int tid = threadIdx.x, w = tid >> 6, lane = tid & 63;
  const int lr = tid >> 2, lk = (tid & 3) * 16;
  const int fm = w * 16 + (lane & 15), fk = (lane >> 4) * 8;
  for (int k0 = kbeg; k0 < kend; k0 += 64) {
    const uint4* ga = (const uint4*)(A + (size_t)(m0 + lr) * LDA + k0 + lk);
    const uint4* gb = (const uint4*)(BT + (size_t)(n0 + lr) * LDB + k0 + lk);
    uint4 a0 = ga[0], a1 = ga[1], b0 = gb[0], b1 = gb[1];
    *(uint4*)&As[lr][lk] = a0;  *(uint4*)&As[lr][lk + 8] = a1;
    *(uint4*)&Bs[lr][lk] = b0;  *(uint4*)&Bs[lr][lk + 8] = b1;
    __syncthreads();
#pragma unroll
    for (int ks = 0; ks < 2; ++ks) {
      bf16x8 af = *(const bf16x8*)&As[fm][ks * 32 + fk];
#pragma unroll
      for (int j = 0; j < 4; ++j) {
        bf16x8 bf = *(const bf16x8*)&Bs[j * 16 + (lane & 15)][ks * 32 + fk];
        acc[j] = __builtin_amdgcn_mfma_f32_16x16x32_bf16(af, bf, acc[j], 0, 0, 0);
      }
    }
    __syncthreads();
  }
}

// ---------------------------------------------------------------------------
// k_gemm12 — a1 and a2 GEMMs in ONE launch, epilogue writes exp(2*val).
// ---------------------------------------------------------------------------
__global__ __launch_bounds__(256)
void k_gemm12(const unsigned short* __restrict__ decb,
              const unsigned short* __restrict__ encpb,
              const unsigned short* __restrict__ WqT,
              const unsigned short* __restrict__ WcT,
              const float* __restrict__ bq,
              float* __restrict__ Ea1, float* __restrict__ Ea2) {
  __shared__ unsigned short As[64][72];
  __shared__ unsigned short Bs[64][72];
  const int tid = threadIdx.x;
  const int w = tid >> 6, lane = tid & 63;

  const bool isA1 = blockIdx.x < 64;
  const int bb = isA1 ? blockIdx.x : blockIdx.x - 64;
  const int n0 = (bb & 7) * 64, m0 = (bb >> 3) * 64;
  const unsigned short* A  = isA1 ? decb : encpb;
  const unsigned short* BT = isA1 ? WqT : WcT;
  float* C = isA1 ? Ea1 : Ea2;

  f32x4 acc[4] = {};
  gemm_tile<512, 512>(A, BT, m0, n0, 0, 512, As, Bs, acc);

  const int col = lane & 15, rq = lane >> 4;
#pragma unroll
  for (int j = 0; j < 4; ++j) {
    const int n = n0 + j * 16 + col;
    const float bv = isA1 ? bq[n] : 0.0f;
#pragma unroll
    for (int r = 0; r < 4; ++r) {
      const int m = m0 + w * 16 + rq * 4 + r;
      float val = acc[j][r] + bv;
      // clamp +-30: Ea product may hit inf, but rcp(inf)=0 is the exact
      // tanh=+-1 limit; no NaN path (both factors positive finite).
      val = fminf(fmaxf(val, -30.0f), 30.0f);
      C[(size_t)m * 512 + n] = __expf(2.0f * val);
    }
  }
}

// ---------------------------------------------------------------------------
// k_scores — sc[b,t,s] = V - sum_h 2 v_h / (Ea1[t,h]*Ea2[s,h] + 1)
// Grid 512 blocks = 8 b x 16 tq(4t) x 4 s-halves(128 s) -> 2 blocks/CU, 8 waves.
// Wave covers 32 s: lane = 16 sl x 4 hq, j-loop of 2 (s = base + j*16 + sl).
// e1 (4t) + v2 register-cached per h-chunk; s is the inner loop -> LDS reads
// per element halved vs r3.
// ---------------------------------------------------------------------------
__global__ __launch_bounds__(256)
void k_scores(const float* __restrict__ Ea1, const float* __restrict__ Ea2,
              const float* __restrict__ v2g, const float* __restrict__ Vsum,
              float* __restrict__ scb) {
  const int blk = blockIdx.x;
  const int b = blk & 7, tq = (blk >> 3) & 15, sh = blk >> 7;   // sh 0..3
  const int tid = threadIdx.x;
  const int wv = tid >> 6, lane = tid & 63;
  const int hq = lane & 3, sl = lane >> 2;

  __shared__ __align__(16) float ea1s[4][HH];
  __shared__ __align__(16) float v2s[HH];

#pragma unroll
  for (int i = 0; i < 4; ++i) {
    const float* row = Ea1 + (size_t)(b * TT + tq * 4 + i) * HH;
    ea1s[i][tid] = row[tid]; ea1s[i][tid + 256] = row[tid + 256];
  }
  v2s[tid] = v2g[tid]; v2s[tid + 256] = v2g[tid + 256];
  __syncthreads();

  const float V = Vsum[0];
  const int s0 = sh * 128 + wv * 32 + sl;         // j adds 16
  const float* e2p0 = Ea2 + (size_t)(b * SS + s0) * HH;
  const float* e2p1 = e2p0 + (size_t)16 * HH;

  float acc[4][2] = {};
#define TERM(E1, E2, VV, A) A = fmaf(VV, __builtin_amdgcn_rcpf(fmaf(E1, E2, 1.0f)), A)
#pragma unroll 4
  for (int it = 0; it < 32; ++it) {
    const int h = it * 16 + hq * 4;
    const float4 e20 = *(const float4*)(e2p0 + h);
    const float4 e21 = *(const float4*)(e2p1 + h);
    const float4 vv  = *(const float4*)&v2s[h];
    float4 e1r[4];
    e1r[0] = *(const float4*)&ea1s[0][h];
    e1r[1] = *(const float4*)&ea1s[1][h];
    e1r[2] = *(const float4*)&ea1s[2][h];
    e1r[3] = *(const float4*)&ea1s[3][h];
#pragma unroll
    for (int i = 0; i < 4; ++i) {
      TERM(e1r[i].x, e20.x, vv.x, acc[i][0]);
      TERM(e1r[i].y, e20.y, vv.y, acc[i][0]);
      TERM(e1r[i].z, e20.z, vv.z, acc[i][0]);
      TERM(e1r[i].w, e20.w, vv.w, acc[i][0]);
      TERM(e1r[i].x, e21.x, vv.x, acc[i][1]);
      TERM(e1r[i].y, e21.y, vv.y, acc[i][1]);
      TERM(e1r[i].z, e21.z, vv.z, acc[i][1]);
      TERM(e1r[i].w, e21.w, vv.w, acc[i][1]);
    }
  }
#undef TERM
#pragma unroll
  for (int i = 0; i < 4; ++i) {
#pragma unroll
    for (int j = 0; j < 2; ++j) {
      acc[i][j] += __shfl_xor(acc[i][j], 1);
      acc[i][j] += __shfl_xor(acc[i][j], 2);
    }
  }
  if (hq == 0) {
#pragma unroll
    for (int i = 0; i < 4; ++i) {
#pragma unroll
      for (int j = 0; j < 2; ++j)
        scb[(size_t)(b * TT + tq * 4 + i) * SS + s0 + j * 16] = V - acc[i][j];
    }
  }
}

// ---------------------------------------------------------------------------
// k_smctx — softmax over S per (b,t) + context, per (b, t-pair), 256 thr.
// ---------------------------------------------------------------------------
__global__ __launch_bounds__(256)
void k_smctx(const float* __restrict__ scb,
             const unsigned short* __restrict__ encpb,
             float* __restrict__ align_out,
             unsigned short* __restrict__ concatb) {
  const int b = blockIdx.x & 7;
  const int t0 = (blockIdx.x >> 3) * 2;
  const int tid = threadIdx.x;
  const int wave = tid >> 6, lane = tid & 63;

  __shared__ __align__(16) float al[2][SS];
  __shared__ float red[2][4];

  const float* r0 = scb + (size_t)(b * TT + t0) * SS;
  const float* r1 = r0 + SS;
  const float x00 = r0[tid], x01 = r0[tid + 256];
  const float x10 = r1[tid], x11 = r1[tid + 256];

  float m0 = fmaxf(x00, x01), m1 = fmaxf(x10, x11);
#pragma unroll
  for (int off = 32; off; off >>= 1) {
    m0 = fmaxf(m0, __shfl_xor(m0, off));
    m1 = fmaxf(m1, __shfl_xor(m1, off));
  }
  if (lane == 0) { red[0][wave] = m0; red[1][wave] = m1; }
  __syncthreads();
  m0 = fmaxf(fmaxf(red[0][0], red[0][1]), fmaxf(red[0][2], red[0][3]));
  m1 = fmaxf(fmaxf(red[1][0], red[1][1]), fmaxf(red[1][2], red[1][3]));
  __syncthreads();

  const float e00 = __expf(x00 - m0), e01 = __expf(x01 - m0);
  const float e10 = __expf(x10 - m1), e11 = __expf(x11 - m1);
  float s0 = e00 + e01, s1 = e10 + e11;
#pragma unroll
  for (int off = 32; off; off >>= 1) {
    s0 += __shfl_xor(s0, off);
    s1 += __shfl_xor(s1, off);
  }
  if (lane == 0) { red[0][wave] = s0; red[1][wave] = s1; }
  __syncthreads();
  s0 = red[0][0] + red[0][1] + red[0][2] + red[0][3];
  s1 = red[1][0] + red[1][1] + red[1][2] + red[1][3];
  const float rs0 = __builtin_amdgcn_rcpf(s0);
  const float rs1 = __builtin_amdgcn_rcpf(s1);

  const float a00 = e00 * rs0, a01 = e01 * rs0;
  const float a10 = e10 * rs1, a11 = e11 * rs1;
  float* ao0 = align_out + (size_t)(t0 + 0) * BB * SS + b * SS;
  float* ao1 = align_out + (size_t)(t0 + 1) * BB * SS + b * SS;
  ao0[tid] = a00; ao0[tid + 256] = a01;
  ao1[tid] = a10; ao1[tid + 256] = a11;
  al[0][tid] = a00; al[0][tid + 256] = a01;
  al[1][tid] = a10; al[1][tid + 256] = a11;
  __syncthreads();

  // context: h = 2*tid, 2*tid+1 via dword loads
  const unsigned* ep = (const unsigned*)(encpb + (size_t)b * SS * HH);
  float c00 = 0.f, c01 = 0.f, c10 = 0.f, c11 = 0.f;
#pragma unroll 16
  for (int s2 = 0; s2 < SS; ++s2) {
    const unsigned u = ep[s2 * 256 + tid];
    const float elo = __uint_as_float(u << 16);
    const float ehi = __uint_as_float(u & 0xffff0000u);
    const float av0 = al[0][s2], av1 = al[1][s2];
    c00 = fmaf(av0, elo, c00); c01 = fmaf(av0, ehi, c01);
    c10 = fmaf(av1, elo, c10); c11 = fmaf(av1, ehi, c11);
  }
  unsigned* cb0 = (unsigned*)(concatb + (size_t)(b * TT + t0) * 1024);
  unsigned* cb1 = (unsigned*)(concatb + (size_t)(b * TT + t0 + 1) * 1024);
  cb0[tid] = (unsigned)f2bf(c00) | ((unsigned)f2bf(c01) << 16);
  cb1[tid] = (unsigned)f2bf(c10) | ((unsigned)f2bf(c11) << 16);
}

// ---------------------------------------------------------------------------
// k_out — attn_h += [c,dec]@Wo, split-K x4 via HW fp32 atomics (bias was
// pre-initialized by k_prep). 256 blocks (64 tiles x 4 K-chunks).
// ---------------------------------------------------------------------------
__global__ __launch_bounds__(256)
void k_out(const unsigned short* __restrict__ A,
           const unsigned short* __restrict__ BT,
           float* __restrict__ C) {
  __shared__ unsigned short As[64][72];
  __shared__ unsigned short Bs[64][72];
  const int tid = threadIdx.x;
  const int w = tid >> 6, lane = tid & 63;
  const int tau = blockIdx.x >> 2, kc = blockIdx.x & 3;
  const int n0 = (tau & 7) * 64, m0 = (tau >> 3) * 64;

  f32x4 acc[4] = {};
  gemm_tile<1024, 1024>(A, BT, m0, n0, kc * 256, kc * 256 + 256, As, Bs, acc);

  const int col = lane & 15, rq = lane >> 4;
#pragma unroll
  for (int j = 0; j < 4; ++j) {
    const int n = n0 + j * 16 + col;
#pragma unroll
    for (int r = 0; r < 4; ++r) {
      const int m = m0 + w * 16 + rq * 4 + r;
      const int bi = m >> 6, t = m & 63;
      unsafeAtomicAdd(&C[(size_t)(t * BB + bi) * 512 + n], acc[j][r]);
    }
  }
}

// ---------------------------------------------------------------------------
extern "C" void kernel_launch(void* const* d_in, const int* in_sizes, int n_in,
                              void* d_out, int out_size, void* d_ws, size_t ws_size,
                              hipStream_t stream) {
  const float* dec  = (const float*)d_in[0];
  const float* enc  = (const float*)d_in[1];
  const float* cov  = (const float*)d_in[2];
  const float* Wq   = (const float*)d_in[3];
  const float* bq   = (const float*)d_in[4];
  const float* Wc   = (const float*)d_in[5];
  const float* v    = (const float*)d_in[6];
  const float* Wo   = (const float*)d_in[7];
  const float* bo   = (const float*)d_in[8];
  const float* wcov = (const float*)d_in[9];

  float* out = (float*)d_out;
  float* attn_h    = out;                         // [T,B,H]
  float* align_out = out + (size_t)TT * BB * HH;  // [T,B,S]

  char* w = (char*)d_ws;
  const size_t MB = 1024 * 1024;
  unsigned short* encpb   = (unsigned short*)(w);            // 4 MB
  unsigned short* WqT     = (unsigned short*)(w + 4 * MB);   // 0.5 MB
  unsigned short* WcT     = (unsigned short*)(w + 5 * MB);   // 0.5 MB
  unsigned short* WoT     = (unsigned short*)(w + 6 * MB);   // 1 MB
  unsigned short* decb    = (unsigned short*)(w + 7 * MB);   // 0.5 MB
  unsigned short* concatb = (unsigned short*)(w + 8 * MB);   // 1 MB
  float*          Ea1     = (float*)(w + 9 * MB);            // 1 MB
  float*          Ea2     = (float*)(w + 10 * MB);           // 8 MB
  float*          scb     = (float*)(w + 18 * MB);           // 1 MB
  float*          v2      = (float*)(w + 19 * MB);           // 2 KB
  float*          Vsum    = (float*)(w + 19 * MB + 4096);    // 4 B

  k_prep<<<10753, 256, 0, stream>>>(enc, cov, wcov, dec, Wq, Wc, Wo, v, bo,
                                    encpb, decb, concatb, WqT, WcT, WoT,
                                    v2, Vsum, attn_h);
  k_gemm12<<<576, 256, 0, stream>>>(decb, encpb, WqT, WcT, bq, Ea1, Ea2);
  k_scores<<<512, 256, 0, stream>>>(Ea1, Ea2, v2, Vsum, scb);
  k_smctx<<<256, 256, 0, stream>>>(scb, encpb, align_out, concatb);
  k_out<<<256, 256, 0, stream>>>(concatb, WoT, attn_h);
}

// Round 7
// 132.936 us; speedup vs baseline: 1.9848x; 1.0832x over previous
//
#include <hip/hip_runtime.h>
#include <cstddef>

static constexpr int TT = 64;    // decoder steps
static constexpr int BB = 8;     // batch
static constexpr int SS = 512;   // source length
static constexpr int HH = 512;   // hidden

typedef __attribute__((ext_vector_type(8))) short bf16x8;
typedef __attribute__((ext_vector_type(4))) float f32x4;

__device__ __forceinline__ float fast_tanh(float x) {
  float e = __expf(2.0f * x);
  return 1.0f - 2.0f * __builtin_amdgcn_rcpf(e + 1.0f);
}
__device__ __forceinline__ unsigned short f2bf(float f) {
  unsigned u = __float_as_uint(f);
  return (unsigned short)((u + 0x7FFFu + ((u >> 16) & 1u)) >> 16);   // RNE
}

// ---------------------------------------------------------------------------
// k_prep — all preprocessing in one launch:
//  [0,8192):     encpb = bf16(tanh(enc + cov*wcov))
//  [8192,8704):  dec pack -> concatb right half (bf16)
//  [8704,9728):  weight transposes Wq,Wc,Wo (32x32 tiles -> WT[n][k] bf16)
// ---------------------------------------------------------------------------
__global__ __launch_bounds__(256)
void k_prep(const float* __restrict__ enc, const float* __restrict__ cov,
            const float* __restrict__ wcov, const float* __restrict__ dec,
            const float* __restrict__ Wq, const float* __restrict__ Wc,
            const float* __restrict__ Wo,
            unsigned short* __restrict__ encpb, unsigned short* __restrict__ concatb,
            unsigned short* __restrict__ WqT, unsigned short* __restrict__ WcT,
            unsigned short* __restrict__ WoT) {
  __shared__ float tile[32][33];
  const int blk = blockIdx.x, tid = threadIdx.x;

  if (blk < 8192) {
    const int idx = blk * 256 + tid;          // over B*S*H
    const int h = idx & 511;
    const int bs = idx >> 9;
    const int s = bs & 511, b = bs >> 9;
    const float x = enc[(size_t)(s * BB + b) * HH + h] + cov[bs] * wcov[h];
    encpb[idx] = f2bf(fast_tanh(x));
  } else if (blk < 8704) {
    const int m = blk - 8192, t = m & 63, b = m >> 6;   // m = b*64+t
    const float2 dv = *(const float2*)(dec + (size_t)(t * BB + b) * HH + 2 * tid);
    ((unsigned*)concatb)[(size_t)m * 512 + 256 + tid] =
        (unsigned)f2bf(dv.x) | ((unsigned)f2bf(dv.y) << 16);
  } else {
    int l = blk - 8704;
    const float* W; unsigned short* WT; int KT;
    if (l < 256)      { W = Wq; WT = WqT; KT = 512; }
    else if (l < 512) { W = Wc; WT = WcT; KT = 512; l -= 256; }
    else              { W = Wo; WT = WoT; KT = 1024; l -= 512; }
    const int n0 = (l & 15) * 32, k0 = (l >> 4) * 32;
    const int r = tid >> 3, c4 = (tid & 7) * 4;
    const float4 w = *(const float4*)(W + (size_t)(k0 + r) * 512 + n0 + c4);
    tile[r][c4 + 0] = w.x; tile[r][c4 + 1] = w.y;
    tile[r][c4 + 2] = w.z; tile[r][c4 + 3] = w.w;
    __syncthreads();
    unsigned short* o = WT + (size_t)(n0 + r) * KT + k0 + c4;
#pragma unroll
    for (int i = 0; i < 4; ++i) o[i] = f2bf(tile[c4 + i][r]);
  }
}

// ---------------------------------------------------------------------------
// 64x64 bf16 MFMA tile over K range. 256 thr / 4 waves.
// C/D layout: col=lane&15, row=(lane>>4)*4+reg (verified r2..r5).
// ---------------------------------------------------------------------------
template<int LDA, int LDB>
__device__ __forceinline__ void gemm_tile(const unsigned short* __restrict__ A,
                                          const unsigned short* __restrict__ BT,
                                          int m0, int n0, int kbeg, int kend,
                                          unsigned short (*As)[72],
                                          unsigned short (*Bs)[72],
                                          f32x4 acc[4]) {
  const int tid = threadIdx.x, w = tid >> 6, lane = tid & 63;
  const int lr = tid >> 2, lk = (tid & 3) * 16;
  const int fm = w * 16 + (lane & 15), fk = (lane >> 4) * 8;
  for (int k0 = kbeg; k0 < kend; k0 += 64) {
    const uint4* ga = (const uint4*)(A + (size_t)(m0 + lr) * LDA + k0 + lk);
    const uint4* gb = (const uint4*)(BT + (size_t)(n0 + lr) * LDB + k0 + lk);
    uint4 a0 = ga[0], a1 = ga[1], b0 = gb[0], b1 = gb[1];
    *(uint4*)&As[lr][lk] = a0;  *(uint4*)&As[lr][lk + 8] = a1;
    *(uint4*)&Bs[lr][lk] = b0;  *(uint4*)&Bs[lr][lk + 8] = b1;
    __syncthreads();
#pragma unroll
    for (int ks = 0; ks < 2; ++ks) {
      bf16x8 af = *(const bf16x8*)&As[fm][ks * 32 + fk];
#pragma unroll
      for (int j = 0; j < 4; ++j) {
        bf16x8 bf = *(const bf16x8*)&Bs[j * 16 + (lane & 15)][ks * 32 + fk];
        acc[j] = __builtin_amdgcn_mfma_f32_16x16x32_bf16(af, bf, acc[j], 0, 0, 0);
      }
    }
    __syncthreads();
  }
}

// ---------------------------------------------------------------------------
// k_gemm12 — three GEMM jobs in ONE launch (640 blocks):
//  g <  64: Ea1 = exp(2*clamp(dec@Wq + bq))          (dec = concatb right half)
//  g < 576: Ea2 = exp(2*clamp(encp@Wc))
//  g < 640: attn_h base = dec@Wo_bot + bo  (scattered [T,B,H]); k_out adds c@Wo_top
// ---------------------------------------------------------------------------
__global__ __launch_bounds__(256)
void k_gemm12(const unsigned short* __restrict__ concatb,
              const unsigned short* __restrict__ encpb,
              const unsigned short* __restrict__ WqT,
              const unsigned short* __restrict__ WcT,
              const unsigned short* __restrict__ WoT,
              const float* __restrict__ bq, const float* __restrict__ bo,
              float* __restrict__ Ea1, float* __restrict__ Ea2,
              float* __restrict__ attn_h) {
  __shared__ unsigned short As[64][72];
  __shared__ unsigned short Bs[64][72];
  const int g = blockIdx.x, tid = threadIdx.x;
  const int w = tid >> 6, lane = tid & 63;
  const int col = lane & 15, rq = lane >> 4;

  if (g < 64) {                        // a1
    const int m0 = (g >> 3) * 64, n0 = (g & 7) * 64;
    f32x4 acc[4] = {};
    gemm_tile<1024, 512>(concatb + 512, WqT, m0, n0, 0, 512, As, Bs, acc);
#pragma unroll
    for (int j = 0; j < 4; ++j) {
      const int n = n0 + j * 16 + col;
      const float bv = bq[n];
#pragma unroll
      for (int r = 0; r < 4; ++r) {
        const int m = m0 + w * 16 + rq * 4 + r;
        // clamp +-30: product may hit inf downstream, rcp(inf)=0 is the exact
        // tanh=+-1 limit; no NaN path (factors positive finite).
        float val = fminf(fmaxf(acc[j][r] + bv, -30.0f), 30.0f);
        Ea1[(size_t)m * 512 + n] = __expf(2.0f * val);
      }
    }
  } else if (g < 576) {                // a2
    const int u = g - 64;
    const int m0 = (u >> 3) * 64, n0 = (u & 7) * 64;
    f32x4 acc[4] = {};
    gemm_tile<512, 512>(encpb, WcT, m0, n0, 0, 512, As, Bs, acc);
#pragma unroll
    for (int j = 0; j < 4; ++j) {
      const int n = n0 + j * 16 + col;
#pragma unroll
      for (int r = 0; r < 4; ++r) {
        const int m = m0 + w * 16 + rq * 4 + r;
        float val = fminf(fmaxf(acc[j][r], -30.0f), 30.0f);
        Ea2[(size_t)m * 512 + n] = __expf(2.0f * val);
      }
    }
  } else {                             // attn_h base = dec@Wo_bot + bo
    const int u = g - 576;
    const int m0 = (u >> 3) * 64, n0 = (u & 7) * 64;
    f32x4 acc[4] = {};
    gemm_tile<1024, 1024>(concatb, WoT, m0, n0, 512, 1024, As, Bs, acc);
#pragma unroll
    for (int j = 0; j < 4; ++j) {
      const int n = n0 + j * 16 + col;
      const float bv = bo[n];
#pragma unroll
      for (int r = 0; r < 4; ++r) {
        const int m = m0 + w * 16 + rq * 4 + r;
        const int bi = m >> 6, t = m & 63;
        attn_h[(size_t)(t * BB + bi) * 512 + n] = acc[j][r] + bv;
      }
    }
  }
}

// ---------------------------------------------------------------------------
// k_attn — scores + softmax + context fused; 256 blocks (b, t-pair), 512 thr.
// Scores: sc[t,s] = -(sum_h 2 v_h / (Ea1[t,h]*Ea2[s,h] + 1))   [V const dropped:
// softmax is shift-invariant].  Stays in LDS.  Softmax -> align_out + LDS.
// Context: wave-halves split s-range, dword bf16 encp loads, LDS combine.
// ---------------------------------------------------------------------------
__global__ __launch_bounds__(512)
void k_attn(const float* __restrict__ Ea1, const float* __restrict__ Ea2,
            const float* __restrict__ v, const unsigned short* __restrict__ encpb,
            float* __restrict__ align_out, unsigned short* __restrict__ concatb) {
  __shared__ __align__(16) char smem[12352];
  float (*sc)[512]   = (float(*)[512])smem;            // [2][512] scores->align
  float (*ea1s)[512] = (float(*)[512])(smem + 4096);   // [2][512] (scores phase)
  float* v2s         = (float*)(smem + 8192);          // [512]    (scores phase)
  float2* part       = (float2*)(smem + 4096);         // [2][2][256] (ctx phase)
  float (*red)[8]    = (float(*)[8])(smem + 12288);    // [2][8]

  const int g = blockIdx.x, tid = threadIdx.x;
  const int b = g & 7, t0 = (g >> 3) * 2;              // XCD-affine b
  const int wv = tid >> 6, lane = tid & 63;
  const int hq = lane & 3, sl = lane >> 2;

  ea1s[0][tid] = Ea1[(size_t)(b * TT + t0) * HH + tid];
  ea1s[1][tid] = Ea1[(size_t)(b * TT + t0 + 1) * HH + tid];
  v2s[tid] = 2.0f * v[tid];
  __syncthreads();

  // ---- scores: 8 waves x 32 s per pass, 2 passes ----
#define TERM(E1, E2, VV, A) A = fmaf(VV, __builtin_amdgcn_rcpf(fmaf(E1, E2, 1.0f)), A)
  for (int p = 0; p < 2; ++p) {
    const int s0 = p * 256 + wv * 32 + sl;             // and s0+16
    const float* e2p0 = Ea2 + (size_t)(b * SS + s0) * HH;
    const float* e2p1 = e2p0 + (size_t)16 * HH;
    float acc[2][2] = {};
#pragma unroll 4
    for (int it = 0; it < 32; ++it) {
      const int h = it * 16 + hq * 4;
      const float4 e20 = *(const float4*)(e2p0 + h);
      const float4 e21 = *(const float4*)(e2p1 + h);
      const float4 vvv = *(const float4*)&v2s[h];
      float4 e1r[2];
      e1r[0] = *(const float4*)&ea1s[0][h];
      e1r[1] = *(const float4*)&ea1s[1][h];
#pragma unroll
      for (int i = 0; i < 2; ++i) {
        TERM(e1r[i].x, e20.x, vvv.x, acc[i][0]);
        TERM(e1r[i].y, e20.y, vvv.y, acc[i][0]);
        TERM(e1r[i].z, e20.z, vvv.z, acc[i][0]);
        TERM(e1r[i].w, e20.w, vvv.w, acc[i][0]);
        TERM(e1r[i].x, e21.x, vvv.x, acc[i][1]);
        TERM(e1r[i].y, e21.y, vvv.y, acc[i][1]);
        TERM(e1r[i].z, e21.z, vvv.z, acc[i][1]);
        TERM(e1r[i].w, e21.w, vvv.w, acc[i][1]);
      }
    }
#pragma unroll
    for (int i = 0; i < 2; ++i)
#pragma unroll
      for (int j = 0; j < 2; ++j) {
        acc[i][j] += __shfl_xor(acc[i][j], 1);
        acc[i][j] += __shfl_xor(acc[i][j], 2);
      }
    if (hq == 0) {
      sc[0][s0] = -acc[0][0]; sc[0][s0 + 16] = -acc[0][1];
      sc[1][s0] = -acc[1][0]; sc[1][s0 + 16] = -acc[1][1];
    }
  }
#undef TERM
  __syncthreads();

  // ---- softmax over s (thread owns s=tid for both t's) ----
  const float x0 = sc[0][tid], x1 = sc[1][tid];
  float m0 = x0, m1 = x1;
#pragma unroll
  for (int off = 32; off; off >>= 1) {
    m0 = fmaxf(m0, __shfl_xor(m0, off));
    m1 = fmaxf(m1, __shfl_xor(m1, off));
  }
  if (lane == 0) { red[0][wv] = m0; red[1][wv] = m1; }
  __syncthreads();
  m0 = red[0][0]; m1 = red[1][0];
#pragma unroll
  for (int w2 = 1; w2 < 8; ++w2) { m0 = fmaxf(m0, red[0][w2]); m1 = fmaxf(m1, red[1][w2]); }
  __syncthreads();
  const float e0 = __expf(x0 - m0), e1 = __expf(x1 - m1);
  float s0v = e0, s1v = e1;
#pragma unroll
  for (int off = 32; off; off >>= 1) {
    s0v += __shfl_xor(s0v, off);
    s1v += __shfl_xor(s1v, off);
  }
  if (lane == 0) { red[0][wv] = s0v; red[1][wv] = s1v; }
  __syncthreads();
  float sum0 = 0.f, sum1 = 0.f;
#pragma unroll
  for (int w2 = 0; w2 < 8; ++w2) { sum0 += red[0][w2]; sum1 += red[1][w2]; }
  const float a0 = e0 * __builtin_amdgcn_rcpf(sum0);
  const float a1 = e1 * __builtin_amdgcn_rcpf(sum1);

  align_out[(size_t)(t0 + 0) * BB * SS + b * SS + tid] = a0;
  align_out[(size_t)(t0 + 1) * BB * SS + b * SS + tid] = a1;
  sc[0][tid] = a0;
  sc[1][tid] = a1;
  __syncthreads();

  // ---- context: sh = s-half (waves 0-3 vs 4-7), hp = h-pair ----
  {
    const int sh = tid >> 8, hp = tid & 255;
    const unsigned* ep = (const unsigned*)encpb + (size_t)b * SS * 256;
    float c00 = 0.f, c01 = 0.f, c10 = 0.f, c11 = 0.f;
#pragma unroll 8
    for (int s2 = sh * 256; s2 < sh * 256 + 256; ++s2) {
      const unsigned u = ep[s2 * 256 + hp];
      const float elo = __uint_as_float(u << 16);
      const float ehi = __uint_as_float(u & 0xffff0000u);
      const float av0 = sc[0][s2], av1 = sc[1][s2];
      c00 = fmaf(av0, elo, c00); c01 = fmaf(av0, ehi, c01);
      c10 = fmaf(av1, elo, c10); c11 = fmaf(av1, ehi, c11);
    }
    part[(0 * 2 + sh) * 256 + hp] = make_float2(c00, c01);
    part[(1 * 2 + sh) * 256 + hp] = make_float2(c10, c11);
  }
  __syncthreads();
  {
    const int t = tid >> 8, hp = tid & 255;
    const float2 pa = part[(t * 2 + 0) * 256 + hp];
    const float2 pb = part[(t * 2 + 1) * 256 + hp];
    const float clo = pa.x + pb.x, chi = pa.y + pb.y;
    ((unsigned*)concatb)[(size_t)(b * TT + t0 + t) * 512 + hp] =
        (unsigned)f2bf(clo) | ((unsigned)f2bf(chi) << 16);
  }
}

// ---------------------------------------------------------------------------
// k_out — attn_h += c@Wo_top (K=512), split-K x4 via HW fp32 atomics on the
// base (dec@Wo_bot + bo) written by k_gemm12. 256 blocks.
// ---------------------------------------------------------------------------
__global__ __launch_bounds__(256)
void k_out(const unsigned short* __restrict__ A,
           const unsigned short* __restrict__ BT,
           float* __restrict__ C) {
  __shared__ unsigned short As[64][72];
  __shared__ unsigned short Bs[64][72];
  const int tid = threadIdx.x;
  const int w = tid >> 6, lane = tid & 63;
  const int tau = blockIdx.x >> 2, kc = blockIdx.x & 3;
  const int n0 = (tau & 7) * 64, m0 = (tau >> 3) * 64;

  f32x4 acc[4] = {};
  gemm_tile<1024, 1024>(A, BT, m0, n0, kc * 128, kc * 128 + 128, As, Bs, acc);

  const int col = lane & 15, rq = lane >> 4;
#pragma unroll
  for (int j = 0; j < 4; ++j) {
    const int n = n0 + j * 16 + col;
#pragma unroll
    for (int r = 0; r < 4; ++r) {
      const int m = m0 + w * 16 + rq * 4 + r;
      const int bi = m >> 6, t = m & 63;
      unsafeAtomicAdd(&C[(size_t)(t * BB + bi) * 512 + n], acc[j][r]);
    }
  }
}

// ---------------------------------------------------------------------------
extern "C" void kernel_launch(void* const* d_in, const int* in_sizes, int n_in,
                              void* d_out, int out_size, void* d_ws, size_t ws_size,
                              hipStream_t stream) {
  const float* dec  = (const float*)d_in[0];
  const float* enc  = (const float*)d_in[1];
  const float* cov  = (const float*)d_in[2];
  const float* Wq   = (const float*)d_in[3];
  const float* bq   = (const float*)d_in[4];
  const float* Wc   = (const float*)d_in[5];
  const float* v    = (const float*)d_in[6];
  const float* Wo   = (const float*)d_in[7];
  const float* bo   = (const float*)d_in[8];
  const float* wcov = (const float*)d_in[9];

  float* out = (float*)d_out;
  float* attn_h    = out;                         // [T,B,H]
  float* align_out = out + (size_t)TT * BB * HH;  // [T,B,S]

  char* w = (char*)d_ws;
  const size_t MB = 1024 * 1024;
  unsigned short* encpb   = (unsigned short*)(w);                      // 4 MB
  unsigned short* WqT     = (unsigned short*)(w + 4 * MB);             // 0.5 MB
  unsigned short* WcT     = (unsigned short*)(w + 4 * MB + 512 * 1024);// 0.5 MB
  unsigned short* WoT     = (unsigned short*)(w + 5 * MB);             // 1 MB [n][1024]
  unsigned short* concatb = (unsigned short*)(w + 6 * MB);             // 1 MB [b*64+t][1024]
  float*          Ea1     = (float*)(w + 7 * MB);                      // 1 MB
  float*          Ea2     = (float*)(w + 8 * MB);                      // 8 MB

  k_prep<<<9728, 256, 0, stream>>>(enc, cov, wcov, dec, Wq, Wc, Wo,
                                   encpb, concatb, WqT, WcT, WoT);
  k_gemm12<<<640, 256, 0, stream>>>(concatb, encpb, WqT, WcT, WoT, bq, bo,
                                    Ea1, Ea2, attn_h);
  k_attn<<<256, 512, 0, stream>>>(Ea1, Ea2, v, encpb, align_out, concatb);
  k_out<<<256, 256, 0, stream>>>(concatb, WoT, attn_h);
}